// Round 6
// baseline (294.355 us; speedup 1.0000x reference)
//
#include <hip/hip_runtime.h>
#include <hip/hip_bf16.h>

#define Dq 1024
#define Hq 4096
#define Tq 4096
#define MAXTILES 40
#define NSTEP 16

// ws layout (bytes)
#define XB_OFF 65536
#define HC_OFF (XB_OFF + Tq * Dq * 2)
#define WT_OFF (HC_OFF + MAXTILES * 128 * Hq * 2)

// meta layout (ints)
#define M_NT 0
#define M_CNT 8
#define M_POFF 16
#define M_CUR 32
#define M_TE 64
#define M_TR 128
#define M_EXP 512
#define M_PERM 4608

typedef __attribute__((ext_vector_type(8))) short bf16x8;
typedef __attribute__((ext_vector_type(4))) float f32x4;

__device__ __forceinline__ short f2bf(float f) {
    __hip_bfloat16 h = __float2bfloat16(f);
    return *reinterpret_cast<short*>(&h);
}

__device__ __forceinline__ float gelu_tanh(float x) {
    float u = 0.7978845608028654f * (x + 0.044715f * x * x * x);
    return x / (1.0f + __expf(-2.0f * u));
}

typedef __attribute__((address_space(1))) const void gvoid;
typedef __attribute__((address_space(3))) void lvoid;
__device__ __forceinline__ void glds16(const void* g, void* l) {
    __builtin_amdgcn_global_load_lds((gvoid*)g, (lvoid*)l, 16, 0, 0);
}

__global__ void k_init(int* meta) {
    int i = blockIdx.x * 256 + threadIdx.x;
    if (i < M_PERM + MAXTILES * 128) meta[i] = 0;
}

// per-expert transpose: in [E][R][C] fp32 -> out [E][C][R] bf16.  64x64 tiles.
__global__ void k_tr(const float* __restrict__ in, short* __restrict__ out, int R, int C) {
    __shared__ float t[64][65];
    int e = blockIdx.z;
    int c0 = blockIdx.x * 64;
    int r0 = blockIdx.y * 64;
    const float* ine = in + (size_t)e * R * C;
    short* oute = out + (size_t)e * R * C;
    int tt = threadIdx.x;
    int lr = tt >> 4;
    int lc = (tt & 15) * 4;
#pragma unroll
    for (int p = 0; p < 4; ++p) {
        int r = p * 16 + lr;
        float4 v = *(const float4*)(ine + (size_t)(r0 + r) * C + c0 + lc);
        t[r][lc] = v.x; t[r][lc + 1] = v.y; t[r][lc + 2] = v.z; t[r][lc + 3] = v.w;
    }
    __syncthreads();
#pragma unroll
    for (int p = 0; p < 4; ++p) {
        int c = p * 16 + lr;
        short4 s;
        s.x = f2bf(t[lc][c]); s.y = f2bf(t[lc + 1][c]);
        s.z = f2bf(t[lc + 2][c]); s.w = f2bf(t[lc + 3][c]);
        *(short4*)(oute + (size_t)(c0 + c) * R + r0 + lc) = s;
    }
}

// route + fold x->bf16 conversion
__global__ void k_route(const float* __restrict__ x, const float* __restrict__ Wg,
                        const float* __restrict__ bg, int* meta, short* __restrict__ xb) {
    int wave = threadIdx.x >> 6;
    int lane = threadIdx.x & 63;
    int t = blockIdx.x * 4 + wave;
    const float* xr = x + (size_t)t * Dq;
    float acc[8];
#pragma unroll
    for (int e = 0; e < 8; ++e) acc[e] = 0.0f;
#pragma unroll
    for (int j = 0; j < 16; ++j) {
        int d = j * 64 + lane;
        float xv = xr[d];
        xb[(size_t)t * Dq + d] = f2bf(xv);
        float4 w0 = *(const float4*)(Wg + (size_t)d * 8);
        float4 w1 = *(const float4*)(Wg + (size_t)d * 8 + 4);
        acc[0] += xv * w0.x; acc[1] += xv * w0.y; acc[2] += xv * w0.z; acc[3] += xv * w0.w;
        acc[4] += xv * w1.x; acc[5] += xv * w1.y; acc[6] += xv * w1.z; acc[7] += xv * w1.w;
    }
#pragma unroll
    for (int e = 0; e < 8; ++e) {
#pragma unroll
        for (int off = 32; off > 0; off >>= 1) acc[e] += __shfl_xor(acc[e], off);
    }
    if (lane == 0) {
        float best = acc[0] + bg[0];
        int be = 0;
#pragma unroll
        for (int e = 1; e < 8; ++e) {
            float v = acc[e] + bg[e];
            if (v > best) { best = v; be = e; }
        }
        meta[M_EXP + t] = be;
        atomicAdd(&meta[M_CNT + be], 1);
    }
}

__global__ void k_scan(int* meta) {
    if (threadIdx.x != 0) return;
    int off = 0, nt = 0;
    for (int e = 0; e < 8; ++e) {
        meta[M_POFF + e] = off;
        int c = meta[M_CNT + e];
        int m = (c + 127) / 128;
        for (int j = 0; j < m; ++j) {
            meta[M_TE + nt] = e;
            meta[M_TR + nt] = off + j * 128;
            ++nt;
        }
        off += m * 128;
    }
    meta[M_POFF + 8] = off;
    meta[M_NT] = nt;
}

__global__ void k_scatter(int* meta) {
    int t = blockIdx.x * 256 + threadIdx.x;
    if (t >= Tq) return;
    int e = meta[M_EXP + t];
    int pos = atomicAdd(&meta[M_CUR + e], 1);
    meta[M_PERM + meta[M_POFF + e] + pos] = t;
}

// per-thread setup: staging addresses (source pre-swizzled) + frag offsets.
// A/B tiles 128 rows x 64 k bf16, LDS linear, read swizzle c^(row&7).
#define GEMM_SETUP()                                                           \
    int tt = threadIdx.x, w = tt >> 6, lane = tt & 63;                         \
    int fr = lane & 15, fg = lane >> 4;                                        \
    int rlo = lane >> 3;                                                       \
    int csw = ((lane & 7) ^ rlo) * 8;                                          \
    int ldsOff[4];                                                             \
    _Pragma("unroll")                                                          \
    for (int s = 0; s < 4; ++s) ldsOff[s] = (s * 32 + w * 8) * 64;             \
    int wm = (w >> 1) * 64, wn = (w & 1) * 64;                                 \
    int aoff[2][4], boff[2][4];                                                \
    _Pragma("unroll")                                                          \
    for (int s2 = 0; s2 < 2; ++s2)                                             \
      _Pragma("unroll")                                                        \
      for (int f = 0; f < 4; ++f) {                                            \
        int c = s2 * 4 + fg;                                                   \
        int m = wm + f * 16 + fr;                                              \
        aoff[s2][f] = m * 64 + ((c ^ (m & 7)) * 8);                            \
        int n = wn + f * 16 + fr;                                              \
        boff[s2][f] = n * 64 + ((c ^ (n & 7)) * 8);                            \
      }                                                                        \
    f32x4 acc[4][4];                                                           \
    _Pragma("unroll")                                                          \
    for (int a = 0; a < 4; ++a)                                                \
      _Pragma("unroll")                                                        \
      for (int b = 0; b < 4; ++b) acc[a][b] = (f32x4){0.f, 0.f, 0.f, 0.f};

// single-buffer K-step: sync(landed) -> read frags -> sync(reads done) ->
// issue glds(t+1) -> MFMA.  Loads fly across MFMA + next-iter entry.
#define KLOOP()                                                                \
  _Pragma("unroll")                                                            \
  for (int t = 0; t < NSTEP; ++t) {                                            \
    __syncthreads();                                                           \
    bf16x8 af[2][4], bv[2][4];                                                 \
    _Pragma("unroll")                                                          \
    for (int s2 = 0; s2 < 2; ++s2)                                             \
      _Pragma("unroll")                                                        \
      for (int f = 0; f < 4; ++f) {                                            \
        af[s2][f] = *(const bf16x8*)(&As[aoff[s2][f]]);                        \
        bv[s2][f] = *(const bf16x8*)(&Bs[boff[s2][f]]);                        \
      }                                                                        \
    __syncthreads();                                                           \
    if (t + 1 < NSTEP) {                                                       \
      _Pragma("unroll")                                                        \
      for (int s = 0; s < 4; ++s) {                                            \
        glds16(aSrc[s] + (t + 1) * 64, As + ldsOff[s]);                        \
        glds16(bSrc[s] + (t + 1) * 64, Bs + ldsOff[s]);                        \
      }                                                                        \
    }                                                                          \
    __builtin_amdgcn_sched_barrier(0);                                         \
    __builtin_amdgcn_s_setprio(1);                                             \
    _Pragma("unroll")                                                          \
    for (int s2 = 0; s2 < 2; ++s2)                                             \
      _Pragma("unroll")                                                        \
      for (int fm = 0; fm < 4; ++fm)                                           \
        _Pragma("unroll")                                                      \
        for (int fn = 0; fn < 4; ++fn)                                         \
          acc[fm][fn] = __builtin_amdgcn_mfma_f32_16x16x32_bf16(               \
              af[s2][fm], bv[s2][fn], acc[fm][fn], 0, 0, 0);                   \
    __builtin_amdgcn_s_setprio(0);                                             \
  }

// ---------------- GEMM1: Hc[i,h] = gelu(sum_d xb[perm[i],d] * W1T[e,h,d]) ----------------
__global__ __launch_bounds__(256, 3) void k_gemm1(const short* __restrict__ xb,
                                                  const short* __restrict__ W1T,
                                                  const int* __restrict__ meta,
                                                  short* __restrict__ Hc) {
    __shared__ short As[128 * 64];
    __shared__ short Bs[128 * 64];
    // 1280 blocks: xcd = hw&7 owns 4 H-panels x 40 tiles
    int hw = blockIdx.x;
    int xcd = hw & 7, q = hw >> 3;          // q 0..159
    int mt = q >> 2;
    int n0 = (xcd * 4 + (q & 3)) * 128;
    if (mt >= meta[M_NT]) return;
    int e = meta[M_TE + mt];
    int i0 = meta[M_TR + mt];
    const int* perm = meta + M_PERM;

    GEMM_SETUP()

    const short* aSrc[4];
    const short* bSrc[4];
#pragma unroll
    for (int s = 0; s < 4; ++s) {
        int row = s * 32 + w * 8 + rlo;
        aSrc[s] = xb + (size_t)perm[i0 + row] * Dq + csw;
        bSrc[s] = W1T + ((size_t)e * Hq + n0 + row) * Dq + csw;
    }

    // prologue: tile 0 in flight
#pragma unroll
    for (int s = 0; s < 4; ++s) {
        glds16(aSrc[s], As + ldsOff[s]);
        glds16(bSrc[s], Bs + ldsOff[s]);
    }

    KLOOP()

    // epilogue: gelu -> bf16 Hc (padded rows hold dup data; never combined)
#pragma unroll
    for (int fm = 0; fm < 4; ++fm) {
        int rbase = i0 + wm + fm * 16 + fg * 4;
#pragma unroll
        for (int fn = 0; fn < 4; ++fn) {
            int col = n0 + wn + fn * 16 + fr;
#pragma unroll
            for (int p = 0; p < 4; ++p) {
                float v = gelu_tanh(acc[fm][fn][p]);
                Hc[(size_t)(rbase + p) * Hq + col] = f2bf(v);
            }
        }
    }
}

// ---------------- GEMM2: out[perm[i],d] += sum_h Hc[i,h] * W2T[e,d,h]  (split-K=4) ----------------
__global__ __launch_bounds__(256, 3) void k_gemm2(const short* __restrict__ Hc,
                                                  const short* __restrict__ W2T,
                                                  const int* __restrict__ meta,
                                                  float* __restrict__ out) {
    __shared__ short As[128 * 64];
    __shared__ short Bs[128 * 64];
    // 1280 blocks: xcd = hw&7 owns 1 D-panel x 40 tiles x 4 K-quarters
    int hw = blockIdx.x;
    int xcd = hw & 7, q = hw >> 3;          // q 0..159
    int mt = q >> 2;
    int sk = q & 3;
    int n0 = xcd * 128;
    int kbase = sk * (Hq / 4);
    if (mt >= meta[M_NT]) return;
    int e = meta[M_TE + mt];
    int i0 = meta[M_TR + mt];
    const int* perm = meta + M_PERM;
    int vend = meta[M_POFF + e] + meta[M_CNT + e];

    GEMM_SETUP()

    const short* aSrc[4];
    const short* bSrc[4];
#pragma unroll
    for (int s = 0; s < 4; ++s) {
        int row = s * 32 + w * 8 + rlo;
        aSrc[s] = Hc + (size_t)(i0 + row) * Hq + kbase + csw;
        bSrc[s] = W2T + ((size_t)e * Dq + n0 + row) * Hq + kbase + csw;
    }

#pragma unroll
    for (int s = 0; s < 4; ++s) {
        glds16(aSrc[s], As + ldsOff[s]);
        glds16(bSrc[s], Bs + ldsOff[s]);
    }

    KLOOP()

    // epilogue: atomic accumulate valid rows into out
#pragma unroll
    for (int fm = 0; fm < 4; ++fm) {
        int rbase = i0 + wm + fm * 16 + fg * 4;
#pragma unroll
        for (int p = 0; p < 4; ++p) {
            int i = rbase + p;
            if (i < vend) {
                int tok = perm[i];
#pragma unroll
                for (int fn = 0; fn < 4; ++fn) {
                    int col = n0 + wn + fn * 16 + fr;
                    atomicAdd(&out[(size_t)tok * Dq + col], acc[fm][fn][p]);
                }
            }
        }
    }
}

extern "C" void kernel_launch(void* const* d_in, const int* in_sizes, int n_in,
                              void* d_out, int out_size, void* d_ws, size_t ws_size,
                              hipStream_t stream) {
    const float* x  = (const float*)d_in[0];
    const float* W1 = (const float*)d_in[1];
    const float* W2 = (const float*)d_in[2];
    const float* Wg = (const float*)d_in[3];
    const float* bg = (const float*)d_in[4];
    float* out = (float*)d_out;
    int* meta = (int*)d_ws;
    short* xb = (short*)((char*)d_ws + XB_OFF);
    short* Hc = (short*)((char*)d_ws + HC_OFF);
    short* WT = (short*)((char*)d_ws + WT_OFF);

    k_init<<<38, 256, 0, stream>>>(meta);
    hipMemsetAsync(d_out, 0, (size_t)Tq * Dq * 4, stream);
    k_route<<<Tq / 4, 256, 0, stream>>>(x, Wg, bg, meta, xb);
    k_scan<<<1, 64, 0, stream>>>(meta);
    k_scatter<<<Tq / 256, 256, 0, stream>>>(meta);
    // W1 [E][Dq][Hq] -> WT [E][Hq][Dq] bf16
    k_tr<<<dim3(Hq / 64, Dq / 64, 8), 256, 0, stream>>>(W1, WT, Dq, Hq);
    k_gemm1<<<1280, 256, 0, stream>>>(xb, WT, meta, Hc);
    // W2 [E][Hq][Dq] -> WT [E][Dq][Hq] bf16 (reuses buffer)
    k_tr<<<dim3(Dq / 64, Hq / 64, 8), 256, 0, stream>>>(W2, WT, Hq, Dq);
    k_gemm2<<<1280, 256, 0, stream>>>(Hc, WT, meta, out);
}